// Round 4
// baseline (1542.879 us; speedup 1.0000x reference)
//
#include <hip/hip_runtime.h>
#include <hip/hip_bf16.h>

// ---------------------------------------------------------------------------
// GNN pretrain forward: h=relu(x@Wl+bl); 5x [gather-agg -> fusedMLP -> BN]
// R8: fused MLP with 2 wide chunks (256 hid cols each) to kill the A-LDS
// re-read amplification (R7: 8 chunks -> every A frag re-read per chunk,
// 256KB LDS reads/wave for a 32KB tile; dominant pipe ~27% of cycles).
//   - A tile 64x256 swizzled (32KB) + hid 64x256 swizzled (32KB) = 64KB LDS,
//     2 blocks/CU, launch_bounds(256,2).
//   - Straight-line: pass1(0); write hid0; [pass2(0) || pass1(1)] as one
//     256-MFMA interleaved phase; write hid1; pass2(1); epilogue.
//   - hid swizzled like As (XOR group^row&7): bank-perfect scalar writes and
//     b128 reads, no pad.
// ---------------------------------------------------------------------------

typedef __bf16 bf16x8 __attribute__((ext_vector_type(8)));
typedef __bf16 bf16x4 __attribute__((ext_vector_type(4)));
typedef float f32x4 __attribute__((ext_vector_type(4)));

#define LDSTRIDE 40  // gemm0 LDS pad

// ------------------- gemm0 (fp32 in, fp32 out, relu) -----------------------
// 128x128 block tile, 4 waves (2x2), each wave 64x64 = 4x4 MFMA tiles.
__global__ __launch_bounds__(256, 2)
void gemm0_kernel(const float* __restrict__ Av, const __bf16* __restrict__ BT,
                  const float* __restrict__ bias, float* __restrict__ Cv,
                  int M, int K, int Nc)
{
    __shared__ __bf16 As[128 * LDSTRIDE];
    __shared__ __bf16 Bs[128 * LDSTRIDE];

    const int tid  = threadIdx.x;
    const int wave = tid >> 6;
    const int lane = tid & 63;
    const int quad = lane >> 4;
    const int l16  = lane & 15;
    const int wm   = wave >> 1;
    const int wn   = wave & 1;

    const int col0 = blockIdx.x * 128;
    const int row0 = blockIdx.y * 128;

    f32x4 acc[4][4];
#pragma unroll
    for (int mt = 0; mt < 4; ++mt)
#pragma unroll
        for (int nt = 0; nt < 4; ++nt) acc[mt][nt] = (f32x4){0.f, 0.f, 0.f, 0.f};

    const int srow = tid >> 1;
    const int scol = (tid & 1) * 16;
    const int a_row = row0 + srow;
    const bool a_ok = (a_row < M);
    const __bf16* Bp = BT + (size_t)(col0 + srow) * K + scol;

    for (int k0 = 0; k0 < K; k0 += 32) {
        bf16x8 a0, a1;
        const float* Ap = Av + (size_t)a_row * K + k0 + scol;
        f32x4 x0 = {0,0,0,0}, x1 = {0,0,0,0}, x2 = {0,0,0,0}, x3 = {0,0,0,0};
        if (a_ok) {
            x0 = *(const f32x4*)(Ap);
            x1 = *(const f32x4*)(Ap + 4);
            x2 = *(const f32x4*)(Ap + 8);
            x3 = *(const f32x4*)(Ap + 12);
        }
#pragma unroll
        for (int j = 0; j < 4; ++j) {
            a0[j] = (__bf16)x0[j]; a0[4 + j] = (__bf16)x1[j];
            a1[j] = (__bf16)x2[j]; a1[4 + j] = (__bf16)x3[j];
        }
        bf16x8 b0 = *(const bf16x8*)(Bp + k0);
        bf16x8 b1 = *(const bf16x8*)(Bp + k0 + 8);

        __syncthreads();
        *(bf16x8*)&As[srow * LDSTRIDE + scol]     = a0;
        *(bf16x8*)&As[srow * LDSTRIDE + scol + 8] = a1;
        *(bf16x8*)&Bs[srow * LDSTRIDE + scol]     = b0;
        *(bf16x8*)&Bs[srow * LDSTRIDE + scol + 8] = b1;
        __syncthreads();

        bf16x8 af[4], bfr[4];
#pragma unroll
        for (int mt = 0; mt < 4; ++mt)
            af[mt] = *(const bf16x8*)&As[(wm * 64 + mt * 16 + l16) * LDSTRIDE + quad * 8];
#pragma unroll
        for (int nt = 0; nt < 4; ++nt)
            bfr[nt] = *(const bf16x8*)&Bs[(wn * 64 + nt * 16 + l16) * LDSTRIDE + quad * 8];

#pragma unroll
        for (int mt = 0; mt < 4; ++mt)
#pragma unroll
            for (int nt = 0; nt < 4; ++nt)
                acc[mt][nt] = __builtin_amdgcn_mfma_f32_16x16x32_bf16(
                    af[mt], bfr[nt], acc[mt][nt], 0, 0, 0);
    }

#pragma unroll
    for (int nt = 0; nt < 4; ++nt) {
        const int col = col0 + wn * 64 + nt * 16 + l16;
        const float b = bias[col];
#pragma unroll
        for (int mt = 0; mt < 4; ++mt) {
#pragma unroll
            for (int r = 0; r < 4; ++r) {
                const int row = row0 + wm * 64 + mt * 16 + quad * 4 + r;
                if (row < M) {
                    float v = fmaxf(acc[mt][nt][r] + b, 0.f);
                    Cv[(size_t)row * Nc + col] = v;
                }
            }
        }
    }
}

// ------------------- fused MLP: out = relu(A@W1+b1)@W2+b2 + BN stats -------
// M-tile = 64 rows/block, 256 threads (4 waves), 2 blocks/CU, 64KB LDS.
// A and hid both 64x256 bf16, XOR-swizzled (8-col group ^ (row&7)).
// 2 chunks of 256 hid cols; overlap phase runs pass2(0)+pass1(1) together.

__global__ __launch_bounds__(256, 2)
void fused_mlp_kernel(const __bf16* __restrict__ aggb,
                      const __bf16* __restrict__ W1T, const float* __restrict__ b1,
                      const __bf16* __restrict__ W2T, const float* __restrict__ b2,
                      float* __restrict__ out, float* __restrict__ sums, int M)
{
    __shared__ __bf16 As[64 * 256];    // 32768 B, swizzled
    __shared__ __bf16 hidS[64 * 256];  // 32768 B, swizzled

    const int tid  = threadIdx.x;
    const int wave = tid >> 6;
    const int lane = tid & 63;
    const int quad = lane >> 4;
    const int l16  = lane & 15;
    const int row0 = blockIdx.x * 64;

    // ---- stage A tile (64 x 256 bf16) into LDS, swizzled ----
    {
        const int srow = tid >> 2;        // 0..63
        const int gb8  = (tid & 3) * 8;   // first 8-col group (0,8,16,24)
        const int m = row0 + srow;
        bf16x8 v[8];
        if (m < M) {
            const __bf16* Ap = aggb + (size_t)m * 256 + gb8 * 8;
#pragma unroll
            for (int j = 0; j < 8; ++j) v[j] = *(const bf16x8*)(Ap + j * 8);
        } else {
#pragma unroll
            for (int j = 0; j < 8; ++j)
#pragma unroll
                for (int q = 0; q < 8; ++q) v[j][q] = (__bf16)0.f;
        }
#pragma unroll
        for (int j = 0; j < 8; ++j) {
            const int sg = (gb8 + j) ^ (srow & 7);
            *(bf16x8*)&As[srow * 256 + sg * 8] = v[j];
        }
    }
    __syncthreads();

    const int cb = wave * 64;  // this wave's col base (pass1 hid cols / pass2 out cols)
    const __bf16* W1p = W1T + (size_t)(cb + l16) * 256 + quad * 8;   // + nt*16*256 + c*256*256 + kk*32
    const __bf16* W2p = W2T + (size_t)(cb + l16) * 512 + quad * 8;   // + nt*16*512 + c*256 + kk*32

    f32x4 acc2[4][4];
#pragma unroll
    for (int mt = 0; mt < 4; ++mt)
#pragma unroll
        for (int nt = 0; nt < 4; ++nt) acc2[mt][nt] = (f32x4){0.f, 0.f, 0.f, 0.f};

    f32x4 acc1[4][4];

    // ================= pass1(0): acc1 = A @ W1[:, chunk0 cols] =================
#pragma unroll
    for (int mt = 0; mt < 4; ++mt)
#pragma unroll
        for (int nt = 0; nt < 4; ++nt) acc1[mt][nt] = (f32x4){0.f, 0.f, 0.f, 0.f};
#pragma unroll
    for (int kk = 0; kk < 8; ++kk) {
        bf16x8 W1f[4];
#pragma unroll
        for (int nt = 0; nt < 4; ++nt)
            W1f[nt] = *(const bf16x8*)(W1p + (size_t)(nt * 16) * 256 + kk * 32);
        const int sg = (kk * 4 + quad) ^ (l16 & 7);
        bf16x8 af[4];
#pragma unroll
        for (int mt = 0; mt < 4; ++mt)
            af[mt] = *(const bf16x8*)&As[(mt * 16 + l16) * 256 + sg * 8];
#pragma unroll
        for (int mt = 0; mt < 4; ++mt)
#pragma unroll
            for (int nt = 0; nt < 4; ++nt)
                acc1[mt][nt] = __builtin_amdgcn_mfma_f32_16x16x32_bf16(
                    af[mt], W1f[nt], acc1[mt][nt], 0, 0, 0);
    }

    // ---- write hid chunk 0 (bias+relu, bf16, swizzled) ----
    {
#pragma unroll
        for (int nt = 0; nt < 4; ++nt) {
            const int col = cb + nt * 16 + l16;           // 0..255 within chunk
            const float bb = b1[col];
            const int colgrp = col >> 3;
            const int c7 = col & 7;
#pragma unroll
            for (int mt = 0; mt < 4; ++mt)
#pragma unroll
                for (int r = 0; r < 4; ++r) {
                    const int row = mt * 16 + quad * 4 + r;
                    float v = fmaxf(acc1[mt][nt][r] + bb, 0.f);
                    hidS[row * 256 + ((colgrp ^ (row & 7)) << 3) + c7] = (__bf16)v;
                }
        }
    }
    __syncthreads();

    // ========= overlap phase: pass2(0) [hid0 @ W2 rows 0..255] =========
    // =========            +  pass1(1) [A @ W1 chunk1 cols]     =========
#pragma unroll
    for (int mt = 0; mt < 4; ++mt)
#pragma unroll
        for (int nt = 0; nt < 4; ++nt) acc1[mt][nt] = (f32x4){0.f, 0.f, 0.f, 0.f};
#pragma unroll
    for (int kk = 0; kk < 8; ++kk) {
        // pass2(0) step kk
        bf16x8 W2f[4];
#pragma unroll
        for (int nt = 0; nt < 4; ++nt)
            W2f[nt] = *(const bf16x8*)(W2p + (size_t)(nt * 16) * 512 + kk * 32);
        const int sg = (kk * 4 + quad) ^ (l16 & 7);
        bf16x8 Hf[4];
#pragma unroll
        for (int mt = 0; mt < 4; ++mt)
            Hf[mt] = *(const bf16x8*)&hidS[(mt * 16 + l16) * 256 + sg * 8];
#pragma unroll
        for (int mt = 0; mt < 4; ++mt)
#pragma unroll
            for (int nt = 0; nt < 4; ++nt)
                acc2[mt][nt] = __builtin_amdgcn_mfma_f32_16x16x32_bf16(
                    Hf[mt], W2f[nt], acc2[mt][nt], 0, 0, 0);

        // pass1(1) step kk
        bf16x8 W1f[4];
#pragma unroll
        for (int nt = 0; nt < 4; ++nt)
            W1f[nt] = *(const bf16x8*)(W1p + (size_t)(256 + nt * 16) * 256 + kk * 32);
        bf16x8 af[4];
#pragma unroll
        for (int mt = 0; mt < 4; ++mt)
            af[mt] = *(const bf16x8*)&As[(mt * 16 + l16) * 256 + sg * 8];
#pragma unroll
        for (int mt = 0; mt < 4; ++mt)
#pragma unroll
            for (int nt = 0; nt < 4; ++nt)
                acc1[mt][nt] = __builtin_amdgcn_mfma_f32_16x16x32_bf16(
                    af[mt], W1f[nt], acc1[mt][nt], 0, 0, 0);
    }
    __syncthreads();  // everyone done READING hid0

    // ---- write hid chunk 1 ----
    {
#pragma unroll
        for (int nt = 0; nt < 4; ++nt) {
            const int col = cb + nt * 16 + l16;
            const float bb = b1[256 + col];
            const int colgrp = col >> 3;
            const int c7 = col & 7;
#pragma unroll
            for (int mt = 0; mt < 4; ++mt)
#pragma unroll
                for (int r = 0; r < 4; ++r) {
                    const int row = mt * 16 + quad * 4 + r;
                    float v = fmaxf(acc1[mt][nt][r] + bb, 0.f);
                    hidS[row * 256 + ((colgrp ^ (row & 7)) << 3) + c7] = (__bf16)v;
                }
        }
    }
    __syncthreads();

    // ================= pass2(1): acc2 += hid1 @ W2 rows 256..511 =================
#pragma unroll
    for (int kk = 0; kk < 8; ++kk) {
        bf16x8 W2f[4];
#pragma unroll
        for (int nt = 0; nt < 4; ++nt)
            W2f[nt] = *(const bf16x8*)(W2p + (size_t)(nt * 16) * 512 + 256 + kk * 32);
        const int sg = (kk * 4 + quad) ^ (l16 & 7);
        bf16x8 Hf[4];
#pragma unroll
        for (int mt = 0; mt < 4; ++mt)
            Hf[mt] = *(const bf16x8*)&hidS[(mt * 16 + l16) * 256 + sg * 8];
#pragma unroll
        for (int mt = 0; mt < 4; ++mt)
#pragma unroll
            for (int nt = 0; nt < 4; ++nt)
                acc2[mt][nt] = __builtin_amdgcn_mfma_f32_16x16x32_bf16(
                    Hf[mt], W2f[nt], acc2[mt][nt], 0, 0, 0);
    }

    // ---- epilogue: bias + store fp32 + BN stats (8-way replicated) ----
    float* srep = sums + (blockIdx.x & 7) * 512;
#pragma unroll
    for (int nt = 0; nt < 4; ++nt) {
        const int col = cb + nt * 16 + l16;
        const float bb = b2[col];
        float s = 0.f, ss = 0.f;
#pragma unroll
        for (int mt = 0; mt < 4; ++mt) {
#pragma unroll
            for (int r = 0; r < 4; ++r) {
                const int row = row0 + mt * 16 + quad * 4 + r;
                if (row < M) {
                    float v = acc2[mt][nt][r] + bb;
                    out[(size_t)row * 256 + col] = v;
                    s += v; ss += v * v;
                }
            }
        }
        s += __shfl_xor(s, 16); ss += __shfl_xor(ss, 16);
        s += __shfl_xor(s, 32); ss += __shfl_xor(ss, 32);
        if (lane < 16) {
            atomicAdd(&srep[col], s);
            atomicAdd(&srep[256 + col], ss);
        }
    }
}

// WT[l][n][k] = (bf16) W[l][k][n]
__global__ void convert_wt_kernel(const float* __restrict__ W, __bf16* __restrict__ WT,
                                  int K, int Nc, int total)
{
    int i = blockIdx.x * 256 + threadIdx.x;
    if (i >= total) return;
    int kn = K * Nc;
    int l = i / kn;
    int rem = i - l * kn;
    int n = rem / K;
    int k = rem - n * K;
    WT[i] = (__bf16)W[(size_t)l * kn + (size_t)k * Nc + n];
}

// ------------------------ edge sort (once per launch) ----------------------

__global__ void zero_counts_kernel(int* __restrict__ counts, int N)
{
    int i = blockIdx.x * 256 + threadIdx.x;
    if (i < N) counts[i] = 0;
}

__global__ void hist_kernel(const int* __restrict__ ei, int* __restrict__ counts, int E)
{
    int e = blockIdx.x * 256 + threadIdx.x;
    if (e < E) atomicAdd(&counts[ei[E + e]], 1);
}

__global__ void scan1_kernel(const int* __restrict__ counts, int* __restrict__ partial,
                             int* __restrict__ blocksums, int N)
{
    __shared__ int sm[256];
    int i = blockIdx.x * 256 + threadIdx.x;
    int v = (i < N) ? counts[i] : 0;
    sm[threadIdx.x] = v;
    __syncthreads();
    for (int off = 1; off < 256; off <<= 1) {
        int t = 0;
        if ((int)threadIdx.x >= off) t = sm[threadIdx.x - off];
        __syncthreads();
        if ((int)threadIdx.x >= off) sm[threadIdx.x] += t;
        __syncthreads();
    }
    if (i < N) partial[i] = sm[threadIdx.x] - v;
    if (threadIdx.x == 255) blocksums[blockIdx.x] = sm[255];
}

__global__ void scan2_kernel(int* __restrict__ blocksums, int NB)
{
    __shared__ int sm[1024];
    int v = ((int)threadIdx.x < NB) ? blocksums[threadIdx.x] : 0;
    sm[threadIdx.x] = v;
    __syncthreads();
    for (int off = 1; off < 1024; off <<= 1) {
        int t = 0;
        if ((int)threadIdx.x >= off) t = sm[threadIdx.x - off];
        __syncthreads();
        if ((int)threadIdx.x >= off) sm[threadIdx.x] += t;
        __syncthreads();
    }
    if ((int)threadIdx.x < NB) blocksums[threadIdx.x] = sm[threadIdx.x] - v;
}

__global__ void scan3_kernel(const int* __restrict__ partial, const int* __restrict__ blocksums,
                             int* __restrict__ rowptr, int* __restrict__ woff, int N, int E)
{
    int i = blockIdx.x * 256 + threadIdx.x;
    if (i < N) {
        int v = partial[i] + blocksums[blockIdx.x];
        rowptr[i] = v;
        woff[i] = v;
    }
    if (i == 0) rowptr[N] = E;
}

__global__ void scatter_sort_kernel(const int* __restrict__ ei, const int* __restrict__ ea,
                                    int* __restrict__ woff, int* __restrict__ sorted, int E)
{
    int e = blockIdx.x * 256 + threadIdx.x;
    if (e >= E) return;
    int dst = ei[E + e];
    int src = ei[e];
    int c = ea[2 * e] * 3 + ea[2 * e + 1];
    int pos = atomicAdd(&woff[dst], 1);
    sorted[pos] = (src << 4) | c;
}

// ------------------------ per-layer kernels --------------------------------

__global__ void build_table_kernel(const float* __restrict__ E1, const float* __restrict__ E2,
                                   int l, float* __restrict__ tab, float* __restrict__ selfemb,
                                   float* __restrict__ sums)
{
    int b = blockIdx.x;
    int t = threadIdx.x;
    const float* e1 = E1 + (size_t)l * 6 * 256;
    const float* e2 = E2 + (size_t)l * 3 * 256;
    if (b < 9) {
        tab[b * 256 + t] = e1[(b / 3) * 256 + t] + e2[(b % 3) * 256 + t];
    } else {
        selfemb[t] = e1[4 * 256 + t] + e2[0 * 256 + t];
#pragma unroll
        for (int r = 0; r < 16; ++r) sums[r * 256 + t] = 0.f;  // 8 replicas x 512
    }
}

// aggb[n] = bf16( bn(out[n]) + selfemb + sum_e (bn(out[src_e]) + tab[c_e]) )
// tab/selfemb read straight from global (10KB, L1-resident). No LDS.
template<int APPLY_BN>
__global__ __launch_bounds__(256)
void gather_kernel(const float* __restrict__ out, const int* __restrict__ rowptr,
                   const int* __restrict__ sorted, const float* __restrict__ tab,
                   const float* __restrict__ selfemb, const float* __restrict__ scsh,
                   __bf16* __restrict__ aggb, int N)
{
    int n = blockIdx.x * 4 + (threadIdx.x >> 6);
    if (n >= N) return;
    int lane = threadIdx.x & 63;
    int f = lane * 4;

    f32x4 sc, sh;
    if (APPLY_BN) {
        sc = *(const f32x4*)(scsh + f);
        sh = *(const f32x4*)(scsh + 256 + f);
    }

    int r0 = rowptr[n];
    int r1 = rowptr[n + 1];

    f32x4 hv = *(const f32x4*)(out + (size_t)n * 256 + f);
    if (APPLY_BN) hv = hv * sc + sh;
    f32x4 acc = hv + *(const f32x4*)(selfemb + f);

    for (int e = r0; e < r1; ++e) {
        int v = sorted[e];
        f32x4 xv = *(const f32x4*)(out + (size_t)(v >> 4) * 256 + f);
        if (APPLY_BN) xv = xv * sc + sh;
        acc += xv + *(const f32x4*)(tab + (v & 15) * 256 + f);
    }
    bf16x4 o;
#pragma unroll
    for (int j = 0; j < 4; ++j) o[j] = (__bf16)acc[j];
    *(bf16x4*)(aggb + (size_t)n * 256 + f) = o;
}

__global__ void bn_finalize_kernel(const float* __restrict__ sums,
                                   const float* __restrict__ gamma,
                                   const float* __restrict__ beta,
                                   int l, int M, float* __restrict__ scsh)
{
    int c = threadIdx.x;  // 256
    float s = 0.f, ss = 0.f;
#pragma unroll
    for (int r = 0; r < 8; ++r) {
        s  += sums[r * 512 + c];
        ss += sums[r * 512 + 256 + c];
    }
    float inv = 1.f / (float)M;
    float mean = s * inv;
    float var = ss * inv - mean * mean;
    float sc = gamma[l * 256 + c] * rsqrtf(var + 1e-5f);
    scsh[c] = sc;
    scsh[256 + c] = beta[l * 256 + c] - mean * sc;
}

// h = out * scale + shift  (final layer only)
__global__ __launch_bounds__(256)
void bn_apply_kernel(const float* __restrict__ out, const float* __restrict__ scsh,
                     float* __restrict__ h, int total4)
{
    int i = blockIdx.x * 256 + threadIdx.x;
    if (i >= total4) return;
    int cg = i & 63;
    f32x4 sc = ((const f32x4*)scsh)[cg];
    f32x4 sh = ((const f32x4*)scsh)[64 + cg];
    f32x4 v = ((const f32x4*)out)[i];
    ((f32x4*)h)[i] = v * sc + sh;
}

extern "C" void kernel_launch(void* const* d_in, const int* in_sizes, int n_in,
                              void* d_out, int out_size, void* d_ws, size_t ws_size,
                              hipStream_t stream)
{
    const float* x     = (const float*)d_in[0];
    const int*   ei    = (const int*)d_in[1];
    const int*   ea    = (const int*)d_in[2];
    const float* Wl    = (const float*)d_in[3];
    const float* bl    = (const float*)d_in[4];
    const float* W1    = (const float*)d_in[5];
    const float* b1    = (const float*)d_in[6];
    const float* W2    = (const float*)d_in[7];
    const float* b2    = (const float*)d_in[8];
    const float* E1    = (const float*)d_in[9];
    const float* E2    = (const float*)d_in[10];
    const float* gamma = (const float*)d_in[11];
    const float* beta  = (const float*)d_in[12];

    const int N = in_sizes[0] / 128;
    const int E = in_sizes[1] / 2;

    // d_out space doubles as the bf16 agg buffer; final bn_apply overwrites it.
    __bf16* aggb = (__bf16*)d_out;               // N x 256 bf16
    float*  hfin = (float*)d_out;                // final output view

    // workspace layout
    float*  out  = (float*)d_ws;                     // N x 256 fp32
    __bf16* WlT  = (__bf16*)(out + (size_t)N * 256); // 256 x 128
    __bf16* W1T  = WlT + 256 * 128;                  // 5 x 512 x 256
    __bf16* W2T  = W1T + 5 * 512 * 256;              // 5 x 256 x 512
    float*  tab  = (float*)(W2T + 5 * 256 * 512);    // 9 x 256
    float*  selfemb = tab + 9 * 256;                 // 256
    float*  sums = selfemb + 256;                    // 8 replicas x 512 = 4096
    float*  scsh = sums + 4096;                      // 512
    int*    counts = (int*)(scsh + 512);             // N
    int*    partial = counts + N;                    // N
    int*    rowptr  = partial + N;                   // N+1
    int*    woff    = rowptr + N + 1;                // N
    int*    sorted  = woff + N;                      // E
    int*    blocksums = sorted + E;                  // <=1024

    const int NB = (N + 255) / 256;
    const int EB = (E + 255) / 256;

    // --- edge sort by dst (edges constant across layers) ---
    zero_counts_kernel<<<NB, 256, 0, stream>>>(counts, N);
    hist_kernel<<<EB, 256, 0, stream>>>(ei, counts, E);
    scan1_kernel<<<NB, 256, 0, stream>>>(counts, partial, blocksums, N);
    scan2_kernel<<<1, 1024, 0, stream>>>(blocksums, NB);
    scan3_kernel<<<NB, 256, 0, stream>>>(partial, blocksums, rowptr, woff, N, E);
    scatter_sort_kernel<<<EB, 256, 0, stream>>>(ei, ea, woff, sorted, E);

    // --- weight conversion (transposed bf16) ---
    convert_wt_kernel<<<(128 * 256 + 255) / 256, 256, 0, stream>>>(Wl, WlT, 128, 256, 128 * 256);
    convert_wt_kernel<<<(5 * 256 * 512 + 255) / 256, 256, 0, stream>>>(W1, W1T, 256, 512, 5 * 256 * 512);
    convert_wt_kernel<<<(5 * 512 * 256 + 255) / 256, 256, 0, stream>>>(W2, W2T, 512, 256, 5 * 512 * 256);

    const int mtiles128 = (N + 127) / 128;
    const int mtiles64  = (N + 63) / 64;
    const int total4 = N * 64;
    const int ew_blocks = (total4 + 255) / 256;
    const int gb = (N + 3) / 4;

    // out = relu(x @ Wl + bl)
    gemm0_kernel<<<dim3(2, mtiles128), 256, 0, stream>>>(x, WlT, bl, out, N, 128, 256);

    for (int l = 0; l < 5; ++l) {
        build_table_kernel<<<10, 256, 0, stream>>>(E1, E2, l, tab, selfemb, sums);
        if (l == 0)
            gather_kernel<0><<<gb, 256, 0, stream>>>(out, rowptr, sorted, tab, selfemb,
                                                     scsh, aggb, N);
        else
            gather_kernel<1><<<gb, 256, 0, stream>>>(out, rowptr, sorted, tab, selfemb,
                                                     scsh, aggb, N);
        fused_mlp_kernel<<<mtiles64, 256, 0, stream>>>(
            aggb, W1T + (size_t)l * 512 * 256, b1 + l * 512,
            W2T + (size_t)l * 256 * 512, b2 + l * 256, out, sums, N);
        bn_finalize_kernel<<<1, 256, 0, stream>>>(sums, gamma, beta, l, N, scsh);
    }
    // final h = bn(out) -> d_out (fp32)
    bn_apply_kernel<<<ew_blocks, 256, 0, stream>>>(out, scsh, hfin, total4);
}

// Round 5
// 1435.778 us; speedup vs baseline: 1.0746x; 1.0746x over previous
//
#include <hip/hip_runtime.h>
#include <hip/hip_bf16.h>

// ---------------------------------------------------------------------------
// GNN pretrain forward: h=relu(x@Wl+bl); 5x [gather-agg -> fusedMLP -> BN]
// R9: latency-exposure round.
//   - fused_mlp: 40KB LDS (A 32KB swz + hid 64x64 swz 8KB single buffer),
//     8 chunks of 64 cols, launch_bounds(256,4) -> 4 blocks/CU = 16 waves/CU.
//     Evidence: dur tracks waves/CU (8w:185, 12w:167); all pipes <15% busy.
//   - gather: edge loop unrolled x4 (4 sorted[] + 4 row loads in flight);
//     was a serial dependent chain at ~600cy L3 latency per edge.
// ---------------------------------------------------------------------------

typedef __bf16 bf16x8 __attribute__((ext_vector_type(8)));
typedef __bf16 bf16x4 __attribute__((ext_vector_type(4)));
typedef float f32x4 __attribute__((ext_vector_type(4)));

#define LDSTRIDE 40  // gemm0 LDS pad

// ------------------- gemm0 (fp32 in, fp32 out, relu) -----------------------
// 128x128 block tile, 4 waves (2x2), each wave 64x64 = 4x4 MFMA tiles.
__global__ __launch_bounds__(256, 2)
void gemm0_kernel(const float* __restrict__ Av, const __bf16* __restrict__ BT,
                  const float* __restrict__ bias, float* __restrict__ Cv,
                  int M, int K, int Nc)
{
    __shared__ __bf16 As[128 * LDSTRIDE];
    __shared__ __bf16 Bs[128 * LDSTRIDE];

    const int tid  = threadIdx.x;
    const int wave = tid >> 6;
    const int lane = tid & 63;
    const int quad = lane >> 4;
    const int l16  = lane & 15;
    const int wm   = wave >> 1;
    const int wn   = wave & 1;

    const int col0 = blockIdx.x * 128;
    const int row0 = blockIdx.y * 128;

    f32x4 acc[4][4];
#pragma unroll
    for (int mt = 0; mt < 4; ++mt)
#pragma unroll
        for (int nt = 0; nt < 4; ++nt) acc[mt][nt] = (f32x4){0.f, 0.f, 0.f, 0.f};

    const int srow = tid >> 1;
    const int scol = (tid & 1) * 16;
    const int a_row = row0 + srow;
    const bool a_ok = (a_row < M);
    const __bf16* Bp = BT + (size_t)(col0 + srow) * K + scol;

    for (int k0 = 0; k0 < K; k0 += 32) {
        bf16x8 a0, a1;
        const float* Ap = Av + (size_t)a_row * K + k0 + scol;
        f32x4 x0 = {0,0,0,0}, x1 = {0,0,0,0}, x2 = {0,0,0,0}, x3 = {0,0,0,0};
        if (a_ok) {
            x0 = *(const f32x4*)(Ap);
            x1 = *(const f32x4*)(Ap + 4);
            x2 = *(const f32x4*)(Ap + 8);
            x3 = *(const f32x4*)(Ap + 12);
        }
#pragma unroll
        for (int j = 0; j < 4; ++j) {
            a0[j] = (__bf16)x0[j]; a0[4 + j] = (__bf16)x1[j];
            a1[j] = (__bf16)x2[j]; a1[4 + j] = (__bf16)x3[j];
        }
        bf16x8 b0 = *(const bf16x8*)(Bp + k0);
        bf16x8 b1 = *(const bf16x8*)(Bp + k0 + 8);

        __syncthreads();
        *(bf16x8*)&As[srow * LDSTRIDE + scol]     = a0;
        *(bf16x8*)&As[srow * LDSTRIDE + scol + 8] = a1;
        *(bf16x8*)&Bs[srow * LDSTRIDE + scol]     = b0;
        *(bf16x8*)&Bs[srow * LDSTRIDE + scol + 8] = b1;
        __syncthreads();

        bf16x8 af[4], bfr[4];
#pragma unroll
        for (int mt = 0; mt < 4; ++mt)
            af[mt] = *(const bf16x8*)&As[(wm * 64 + mt * 16 + l16) * LDSTRIDE + quad * 8];
#pragma unroll
        for (int nt = 0; nt < 4; ++nt)
            bfr[nt] = *(const bf16x8*)&Bs[(wn * 64 + nt * 16 + l16) * LDSTRIDE + quad * 8];

#pragma unroll
        for (int mt = 0; mt < 4; ++mt)
#pragma unroll
            for (int nt = 0; nt < 4; ++nt)
                acc[mt][nt] = __builtin_amdgcn_mfma_f32_16x16x32_bf16(
                    af[mt], bfr[nt], acc[mt][nt], 0, 0, 0);
    }

#pragma unroll
    for (int nt = 0; nt < 4; ++nt) {
        const int col = col0 + wn * 64 + nt * 16 + l16;
        const float b = bias[col];
#pragma unroll
        for (int mt = 0; mt < 4; ++mt) {
#pragma unroll
            for (int r = 0; r < 4; ++r) {
                const int row = row0 + wm * 64 + mt * 16 + quad * 4 + r;
                if (row < M) {
                    float v = fmaxf(acc[mt][nt][r] + b, 0.f);
                    Cv[(size_t)row * Nc + col] = v;
                }
            }
        }
    }
}

// ------------------- fused MLP: out = relu(A@W1+b1)@W2+b2 + BN stats -------
// M-tile = 64 rows/block, 256 threads (4 waves), 4 blocks/CU (40KB LDS).
// A: 64x256 swizzled (group ^ row&7). hid: 64x64 swizzled single buffer.
// 8 chunks of 64 hid cols; per iter: pass2(c-1) -> barrier -> pass1(c) ->
// write hid(c) -> barrier.

__global__ __launch_bounds__(256, 4)
void fused_mlp_kernel(const __bf16* __restrict__ aggb,
                      const __bf16* __restrict__ W1T, const float* __restrict__ b1,
                      const __bf16* __restrict__ W2T, const float* __restrict__ b2,
                      float* __restrict__ out, float* __restrict__ sums, int M)
{
    __shared__ __bf16 As[64 * 256];   // 32768 B, swizzled
    __shared__ __bf16 hidS[64 * 64];  // 8192 B, swizzled

    const int tid  = threadIdx.x;
    const int wave = tid >> 6;
    const int lane = tid & 63;
    const int quad = lane >> 4;
    const int l16  = lane & 15;
    const int row0 = blockIdx.x * 64;

    // ---- stage A tile (64 x 256 bf16) into LDS, swizzled ----
    {
        const int srow = tid >> 2;        // 0..63
        const int gb8  = (tid & 3) * 8;   // first 8-col group (0,8,16,24)
        const int m = row0 + srow;
        bf16x8 v[8];
        if (m < M) {
            const __bf16* Ap = aggb + (size_t)m * 256 + gb8 * 8;
#pragma unroll
            for (int j = 0; j < 8; ++j) v[j] = *(const bf16x8*)(Ap + j * 8);
        } else {
#pragma unroll
            for (int j = 0; j < 8; ++j)
#pragma unroll
                for (int q = 0; q < 8; ++q) v[j][q] = (__bf16)0.f;
        }
#pragma unroll
        for (int j = 0; j < 8; ++j) {
            const int sg = (gb8 + j) ^ (srow & 7);
            *(bf16x8*)&As[srow * 256 + sg * 8] = v[j];
        }
    }
    __syncthreads();

    const int cb = wave * 64;  // pass2 output column base
    f32x4 acc2[4][4];
#pragma unroll
    for (int mt = 0; mt < 4; ++mt)
#pragma unroll
        for (int nt = 0; nt < 4; ++nt) acc2[mt][nt] = (f32x4){0.f, 0.f, 0.f, 0.f};

    // pass1: wave covers hid cols c*64 + wave*16 + l16
    const __bf16* W1p = W1T + (size_t)(wave * 16 + l16) * 256 + quad * 8;
    const __bf16* W2p = W2T + (size_t)(cb + l16) * 512 + quad * 8;

#pragma unroll 1
    for (int c = 0; c <= 8; ++c) {
        // ---- pass2(c-1): acc2 += hid(c-1) @ W2[(c-1)*64 .. +64, :] ----
        if (c >= 1) {
#pragma unroll
            for (int kkl = 0; kkl < 2; ++kkl) {
                bf16x8 W2f[4], Hf[4];
#pragma unroll
                for (int nt = 0; nt < 4; ++nt)
                    W2f[nt] = *(const bf16x8*)(W2p + (size_t)(nt * 16) * 512
                                               + (c - 1) * 64 + kkl * 32);
#pragma unroll
                for (int mt = 0; mt < 4; ++mt) {
                    const int row = mt * 16 + l16;
                    const int sg = (kkl * 4 + quad) ^ (row & 7);
                    Hf[mt] = *(const bf16x8*)&hidS[row * 64 + sg * 8];
                }
#pragma unroll
                for (int mt = 0; mt < 4; ++mt)
#pragma unroll
                    for (int nt = 0; nt < 4; ++nt)
                        acc2[mt][nt] = __builtin_amdgcn_mfma_f32_16x16x32_bf16(
                            Hf[mt], W2f[nt], acc2[mt][nt], 0, 0, 0);
            }
        }

        if (c < 8) {
            __syncthreads();  // all waves done READING hid(c-1)

            // ---- pass1(c): acc1 = A @ W1[:, c*64 + wave*16 .. +16) ----
            f32x4 acc1[4];
#pragma unroll
            for (int mt = 0; mt < 4; ++mt) acc1[mt] = (f32x4){0.f, 0.f, 0.f, 0.f};
            const __bf16* p = W1p + (size_t)(c * 64) * 256;
#pragma unroll
            for (int kk = 0; kk < 8; ++kk) {
                bf16x8 W1f = *(const bf16x8*)(p + kk * 32);
                const int sg = (kk * 4 + quad) ^ (l16 & 7);
                bf16x8 af[4];
#pragma unroll
                for (int mt = 0; mt < 4; ++mt)
                    af[mt] = *(const bf16x8*)&As[(mt * 16 + l16) * 256 + sg * 8];
#pragma unroll
                for (int mt = 0; mt < 4; ++mt)
                    acc1[mt] = __builtin_amdgcn_mfma_f32_16x16x32_bf16(
                        af[mt], W1f, acc1[mt], 0, 0, 0);
            }

            // ---- write hid(c): logical col = wave*16 + l16, swizzled ----
            {
                const int lcol = wave * 16 + l16;
                const float bb = b1[c * 64 + lcol];
                const int colgrp = lcol >> 3;
                const int c7 = lcol & 7;
#pragma unroll
                for (int mt = 0; mt < 4; ++mt)
#pragma unroll
                    for (int r = 0; r < 4; ++r) {
                        const int row = mt * 16 + quad * 4 + r;
                        float v = fmaxf(acc1[mt][r] + bb, 0.f);
                        hidS[row * 64 + ((colgrp ^ (row & 7)) << 3) + c7] = (__bf16)v;
                    }
            }
            __syncthreads();  // hid(c) visible before pass2(c)
        }
    }

    // ---- epilogue: bias + store fp32 + BN stats (8-way replicated) ----
    float* srep = sums + (blockIdx.x & 7) * 512;
#pragma unroll
    for (int nt = 0; nt < 4; ++nt) {
        const int col = cb + nt * 16 + l16;
        const float bb = b2[col];
        float s = 0.f, ss = 0.f;
#pragma unroll
        for (int mt = 0; mt < 4; ++mt) {
#pragma unroll
            for (int r = 0; r < 4; ++r) {
                const int row = row0 + mt * 16 + quad * 4 + r;
                if (row < M) {
                    float v = acc2[mt][nt][r] + bb;
                    out[(size_t)row * 256 + col] = v;
                    s += v; ss += v * v;
                }
            }
        }
        s += __shfl_xor(s, 16); ss += __shfl_xor(ss, 16);
        s += __shfl_xor(s, 32); ss += __shfl_xor(ss, 32);
        if (lane < 16) {
            atomicAdd(&srep[col], s);
            atomicAdd(&srep[256 + col], ss);
        }
    }
}

// WT[l][n][k] = (bf16) W[l][k][n]
__global__ void convert_wt_kernel(const float* __restrict__ W, __bf16* __restrict__ WT,
                                  int K, int Nc, int total)
{
    int i = blockIdx.x * 256 + threadIdx.x;
    if (i >= total) return;
    int kn = K * Nc;
    int l = i / kn;
    int rem = i - l * kn;
    int n = rem / K;
    int k = rem - n * K;
    WT[i] = (__bf16)W[(size_t)l * kn + (size_t)k * Nc + n];
}

// ------------------------ edge sort (once per launch) ----------------------

__global__ void zero_counts_kernel(int* __restrict__ counts, int N)
{
    int i = blockIdx.x * 256 + threadIdx.x;
    if (i < N) counts[i] = 0;
}

__global__ void hist_kernel(const int* __restrict__ ei, int* __restrict__ counts, int E)
{
    int e = blockIdx.x * 256 + threadIdx.x;
    if (e < E) atomicAdd(&counts[ei[E + e]], 1);
}

__global__ void scan1_kernel(const int* __restrict__ counts, int* __restrict__ partial,
                             int* __restrict__ blocksums, int N)
{
    __shared__ int sm[256];
    int i = blockIdx.x * 256 + threadIdx.x;
    int v = (i < N) ? counts[i] : 0;
    sm[threadIdx.x] = v;
    __syncthreads();
    for (int off = 1; off < 256; off <<= 1) {
        int t = 0;
        if ((int)threadIdx.x >= off) t = sm[threadIdx.x - off];
        __syncthreads();
        if ((int)threadIdx.x >= off) sm[threadIdx.x] += t;
        __syncthreads();
    }
    if (i < N) partial[i] = sm[threadIdx.x] - v;
    if (threadIdx.x == 255) blocksums[blockIdx.x] = sm[255];
}

__global__ void scan2_kernel(int* __restrict__ blocksums, int NB)
{
    __shared__ int sm[1024];
    int v = ((int)threadIdx.x < NB) ? blocksums[threadIdx.x] : 0;
    sm[threadIdx.x] = v;
    __syncthreads();
    for (int off = 1; off < 1024; off <<= 1) {
        int t = 0;
        if ((int)threadIdx.x >= off) t = sm[threadIdx.x - off];
        __syncthreads();
        if ((int)threadIdx.x >= off) sm[threadIdx.x] += t;
        __syncthreads();
    }
    if ((int)threadIdx.x < NB) blocksums[threadIdx.x] = sm[threadIdx.x] - v;
}

__global__ void scan3_kernel(const int* __restrict__ partial, const int* __restrict__ blocksums,
                             int* __restrict__ rowptr, int* __restrict__ woff, int N, int E)
{
    int i = blockIdx.x * 256 + threadIdx.x;
    if (i < N) {
        int v = partial[i] + blocksums[blockIdx.x];
        rowptr[i] = v;
        woff[i] = v;
    }
    if (i == 0) rowptr[N] = E;
}

__global__ void scatter_sort_kernel(const int* __restrict__ ei, const int* __restrict__ ea,
                                    int* __restrict__ woff, int* __restrict__ sorted, int E)
{
    int e = blockIdx.x * 256 + threadIdx.x;
    if (e >= E) return;
    int dst = ei[E + e];
    int src = ei[e];
    int c = ea[2 * e] * 3 + ea[2 * e + 1];
    int pos = atomicAdd(&woff[dst], 1);
    sorted[pos] = (src << 4) | c;
}

// ------------------------ per-layer kernels --------------------------------

__global__ void build_table_kernel(const float* __restrict__ E1, const float* __restrict__ E2,
                                   int l, float* __restrict__ tab, float* __restrict__ selfemb,
                                   float* __restrict__ sums)
{
    int b = blockIdx.x;
    int t = threadIdx.x;
    const float* e1 = E1 + (size_t)l * 6 * 256;
    const float* e2 = E2 + (size_t)l * 3 * 256;
    if (b < 9) {
        tab[b * 256 + t] = e1[(b / 3) * 256 + t] + e2[(b % 3) * 256 + t];
    } else {
        selfemb[t] = e1[4 * 256 + t] + e2[0 * 256 + t];
#pragma unroll
        for (int r = 0; r < 16; ++r) sums[r * 256 + t] = 0.f;  // 8 replicas x 512
    }
}

// aggb[n] = bf16( bn(out[n]) + selfemb + sum_e (bn(out[src_e]) + tab[c_e]) )
// Edge loop unrolled x4: 4 sorted[] + 4 row loads in flight (was a serial
// dependent chain at L3 latency per edge).
template<int APPLY_BN>
__global__ __launch_bounds__(256)
void gather_kernel(const float* __restrict__ out, const int* __restrict__ rowptr,
                   const int* __restrict__ sorted, const float* __restrict__ tab,
                   const float* __restrict__ selfemb, const float* __restrict__ scsh,
                   __bf16* __restrict__ aggb, int N)
{
    int n = blockIdx.x * 4 + (threadIdx.x >> 6);
    if (n >= N) return;
    int lane = threadIdx.x & 63;
    int f = lane * 4;

    f32x4 sc, sh;
    if (APPLY_BN) {
        sc = *(const f32x4*)(scsh + f);
        sh = *(const f32x4*)(scsh + 256 + f);
    }

    int r0 = rowptr[n];
    int r1 = rowptr[n + 1];

    f32x4 hv = *(const f32x4*)(out + (size_t)n * 256 + f);
    if (APPLY_BN) hv = hv * sc + sh;
    f32x4 acc = hv + *(const f32x4*)(selfemb + f);

    int e = r0;
#pragma unroll 1
    for (; e + 4 <= r1; e += 4) {
        int v0 = sorted[e + 0];
        int v1 = sorted[e + 1];
        int v2 = sorted[e + 2];
        int v3 = sorted[e + 3];
        f32x4 x0 = *(const f32x4*)(out + (size_t)(v0 >> 4) * 256 + f);
        f32x4 x1 = *(const f32x4*)(out + (size_t)(v1 >> 4) * 256 + f);
        f32x4 x2 = *(const f32x4*)(out + (size_t)(v2 >> 4) * 256 + f);
        f32x4 x3 = *(const f32x4*)(out + (size_t)(v3 >> 4) * 256 + f);
        f32x4 t0 = *(const f32x4*)(tab + (v0 & 15) * 256 + f);
        f32x4 t1 = *(const f32x4*)(tab + (v1 & 15) * 256 + f);
        f32x4 t2 = *(const f32x4*)(tab + (v2 & 15) * 256 + f);
        f32x4 t3 = *(const f32x4*)(tab + (v3 & 15) * 256 + f);
        if (APPLY_BN) {
            x0 = x0 * sc + sh; x1 = x1 * sc + sh;
            x2 = x2 * sc + sh; x3 = x3 * sc + sh;
        }
        acc += (x0 + t0) + (x1 + t1);
        acc += (x2 + t2) + (x3 + t3);
    }
#pragma unroll 1
    for (; e < r1; ++e) {
        int v = sorted[e];
        f32x4 xv = *(const f32x4*)(out + (size_t)(v >> 4) * 256 + f);
        if (APPLY_BN) xv = xv * sc + sh;
        acc += xv + *(const f32x4*)(tab + (v & 15) * 256 + f);
    }
    bf16x4 o;
#pragma unroll
    for (int j = 0; j < 4; ++j) o[j] = (__bf16)acc[j];
    *(bf16x4*)(aggb + (size_t)n * 256 + f) = o;
}

__global__ void bn_finalize_kernel(const float* __restrict__ sums,
                                   const float* __restrict__ gamma,
                                   const float* __restrict__ beta,
                                   int l, int M, float* __restrict__ scsh)
{
    int c = threadIdx.x;  // 256
    float s = 0.f, ss = 0.f;
#pragma unroll
    for (int r = 0; r < 8; ++r) {
        s  += sums[r * 512 + c];
        ss += sums[r * 512 + 256 + c];
    }
    float inv = 1.f / (float)M;
    float mean = s * inv;
    float var = ss * inv - mean * mean;
    float sc = gamma[l * 256 + c] * rsqrtf(var + 1e-5f);
    scsh[c] = sc;
    scsh[256 + c] = beta[l * 256 + c] - mean * sc;
}

// h = out * scale + shift  (final layer only)
__global__ __launch_bounds__(256)
void bn_apply_kernel(const float* __restrict__ out, const float* __restrict__ scsh,
                     float* __restrict__ h, int total4)
{
    int i = blockIdx.x * 256 + threadIdx.x;
    if (i >= total4) return;
    int cg = i & 63;
    f32x4 sc = ((const f32x4*)scsh)[cg];
    f32x4 sh = ((const f32x4*)scsh)[64 + cg];
    f32x4 v = ((const f32x4*)out)[i];
    ((f32x4*)h)[i] = v * sc + sh;
}

extern "C" void kernel_launch(void* const* d_in, const int* in_sizes, int n_in,
                              void* d_out, int out_size, void* d_ws, size_t ws_size,
                              hipStream_t stream)
{
    const float* x     = (const float*)d_in[0];
    const int*   ei    = (const int*)d_in[1];
    const int*   ea    = (const int*)d_in[2];
    const float* Wl    = (const float*)d_in[3];
    const float* bl    = (const float*)d_in[4];
    const float* W1    = (const float*)d_in[5];
    const float* b1    = (const float*)d_in[6];
    const float* W2    = (const float*)d_in[7];
    const float* b2    = (const float*)d_in[8];
    const float* E1    = (const float*)d_in[9];
    const float* E2    = (const float*)d_in[10];
    const float* gamma = (const float*)d_in[11];
    const float* beta  = (const float*)d_in[12];

    const int N = in_sizes[0] / 128;
    const int E = in_sizes[1] / 2;

    // d_out space doubles as the bf16 agg buffer; final bn_apply overwrites it.
    __bf16* aggb = (__bf16*)d_out;               // N x 256 bf16
    float*  hfin = (float*)d_out;                // final output view

    // workspace layout
    float*  out  = (float*)d_ws;                     // N x 256 fp32
    __bf16* WlT  = (__bf16*)(out + (size_t)N * 256); // 256 x 128
    __bf16* W1T  = WlT + 256 * 128;                  // 5 x 512 x 256
    __bf16* W2T  = W1T + 5 * 512 * 256;              // 5 x 256 x 512
    float*  tab  = (float*)(W2T + 5 * 256 * 512);    // 9 x 256
    float*  selfemb = tab + 9 * 256;                 // 256
    float*  sums = selfemb + 256;                    // 8 replicas x 512 = 4096
    float*  scsh = sums + 4096;                      // 512
    int*    counts = (int*)(scsh + 512);             // N
    int*    partial = counts + N;                    // N
    int*    rowptr  = partial + N;                   // N+1
    int*    woff    = rowptr + N + 1;                // N
    int*    sorted  = woff + N;                      // E
    int*    blocksums = sorted + E;                  // <=1024

    const int NB = (N + 255) / 256;
    const int EB = (E + 255) / 256;

    // --- edge sort by dst (edges constant across layers) ---
    zero_counts_kernel<<<NB, 256, 0, stream>>>(counts, N);
    hist_kernel<<<EB, 256, 0, stream>>>(ei, counts, E);
    scan1_kernel<<<NB, 256, 0, stream>>>(counts, partial, blocksums, N);
    scan2_kernel<<<1, 1024, 0, stream>>>(blocksums, NB);
    scan3_kernel<<<NB, 256, 0, stream>>>(partial, blocksums, rowptr, woff, N, E);
    scatter_sort_kernel<<<EB, 256, 0, stream>>>(ei, ea, woff, sorted, E);

    // --- weight conversion (transposed bf16) ---
    convert_wt_kernel<<<(128 * 256 + 255) / 256, 256, 0, stream>>>(Wl, WlT, 128, 256, 128 * 256);
    convert_wt_kernel<<<(5 * 256 * 512 + 255) / 256, 256, 0, stream>>>(W1, W1T, 256, 512, 5 * 256 * 512);
    convert_wt_kernel<<<(5 * 512 * 256 + 255) / 256, 256, 0, stream>>>(W2, W2T, 512, 256, 5 * 512 * 256);

    const int mtiles128 = (N + 127) / 128;
    const int mtiles64  = (N + 63) / 64;
    const int total4 = N * 64;
    const int ew_blocks = (total4 + 255) / 256;
    const int gb = (N + 3) / 4;

    // out = relu(x @ Wl + bl)
    gemm0_kernel<<<dim3(2, mtiles128), 256, 0, stream>>>(x, WlT, bl, out, N, 128, 256);

    for (int l = 0; l < 5; ++l) {
        build_table_kernel<<<10, 256, 0, stream>>>(E1, E2, l, tab, selfemb, sums);
        if (l == 0)
            gather_kernel<0><<<gb, 256, 0, stream>>>(out, rowptr, sorted, tab, selfemb,
                                                     scsh, aggb, N);
        else
            gather_kernel<1><<<gb, 256, 0, stream>>>(out, rowptr, sorted, tab, selfemb,
                                                     scsh, aggb, N);
        fused_mlp_kernel<<<mtiles64, 256, 0, stream>>>(
            aggb, W1T + (size_t)l * 512 * 256, b1 + l * 512,
            W2T + (size_t)l * 256 * 512, b2 + l * 256, out, sums, N);
        bn_finalize_kernel<<<1, 256, 0, stream>>>(sums, gamma, beta, l, N, scsh);
    }
    // final h = bn(out) -> d_out (fp32)
    bn_apply_kernel<<<ew_blocks, 256, 0, stream>>>(out, scsh, hfin, total4);
}

// Round 7
// 1359.081 us; speedup vs baseline: 1.1352x; 1.0564x over previous
//
#include <hip/hip_runtime.h>
#include <hip/hip_bf16.h>

// ---------------------------------------------------------------------------
// GNN pretrain forward: h=relu(x@Wl+bl); 5x [gather-agg -> fusedMLP -> BN]
// R11 = R10 resubmit (round 6 bench was an infra failure: "container failed
// twice", no pytest/compile output; kernel never measured. Source re-audited:
// barriers, swizzle bijectivity, VGPR budget, 96KB LDS precedent all OK).
// R10: fused MLP with M-tile=128 (512 thr, 8 waves) + deep register prefetch.
// Evidence: dur insensitive to occupancy (8w:185,12w:164,16w:175); all pipes
// <15% busy; R9's VGPR=64 cap serialized its 128 weight-loads/wave. Fix:
// halve loads/row (M=128: 4 load-inst/row vs 8) and give the compiler 256
// VGPRs (2/SIMD) with explicit W1(c+1)/W2(c) prefetch hidden under MFMAs.
//   - A 128x256 swz (64KB) + hid 128x128 swz (32KB) = 96KB LDS, 1 block/CU.
//   - 4 chunks of 128 hid cols, fully unrolled; 2 barriers/chunk.
//   - gather keeps R9's x4-unrolled edge loop (saved ~16us/layer).
// ---------------------------------------------------------------------------

typedef __bf16 bf16x8 __attribute__((ext_vector_type(8)));
typedef __bf16 bf16x4 __attribute__((ext_vector_type(4)));
typedef float f32x4 __attribute__((ext_vector_type(4)));

#define LDSTRIDE 40  // gemm0 LDS pad

// ------------------- gemm0 (fp32 in, fp32 out, relu) -----------------------
// 128x128 block tile, 4 waves (2x2), each wave 64x64 = 4x4 MFMA tiles.
__global__ __launch_bounds__(256, 2)
void gemm0_kernel(const float* __restrict__ Av, const __bf16* __restrict__ BT,
                  const float* __restrict__ bias, float* __restrict__ Cv,
                  int M, int K, int Nc)
{
    __shared__ __bf16 As[128 * LDSTRIDE];
    __shared__ __bf16 Bs[128 * LDSTRIDE];

    const int tid  = threadIdx.x;
    const int wave = tid >> 6;
    const int lane = tid & 63;
    const int quad = lane >> 4;
    const int l16  = lane & 15;
    const int wm   = wave >> 1;
    const int wn   = wave & 1;

    const int col0 = blockIdx.x * 128;
    const int row0 = blockIdx.y * 128;

    f32x4 acc[4][4];
#pragma unroll
    for (int mt = 0; mt < 4; ++mt)
#pragma unroll
        for (int nt = 0; nt < 4; ++nt) acc[mt][nt] = (f32x4){0.f, 0.f, 0.f, 0.f};

    const int srow = tid >> 1;
    const int scol = (tid & 1) * 16;
    const int a_row = row0 + srow;
    const bool a_ok = (a_row < M);
    const __bf16* Bp = BT + (size_t)(col0 + srow) * K + scol;

    for (int k0 = 0; k0 < K; k0 += 32) {
        bf16x8 a0, a1;
        const float* Ap = Av + (size_t)a_row * K + k0 + scol;
        f32x4 x0 = {0,0,0,0}, x1 = {0,0,0,0}, x2 = {0,0,0,0}, x3 = {0,0,0,0};
        if (a_ok) {
            x0 = *(const f32x4*)(Ap);
            x1 = *(const f32x4*)(Ap + 4);
            x2 = *(const f32x4*)(Ap + 8);
            x3 = *(const f32x4*)(Ap + 12);
        }
#pragma unroll
        for (int j = 0; j < 4; ++j) {
            a0[j] = (__bf16)x0[j]; a0[4 + j] = (__bf16)x1[j];
            a1[j] = (__bf16)x2[j]; a1[4 + j] = (__bf16)x3[j];
        }
        bf16x8 b0 = *(const bf16x8*)(Bp + k0);
        bf16x8 b1 = *(const bf16x8*)(Bp + k0 + 8);

        __syncthreads();
        *(bf16x8*)&As[srow * LDSTRIDE + scol]     = a0;
        *(bf16x8*)&As[srow * LDSTRIDE + scol + 8] = a1;
        *(bf16x8*)&Bs[srow * LDSTRIDE + scol]     = b0;
        *(bf16x8*)&Bs[srow * LDSTRIDE + scol + 8] = b1;
        __syncthreads();

        bf16x8 af[4], bfr[4];
#pragma unroll
        for (int mt = 0; mt < 4; ++mt)
            af[mt] = *(const bf16x8*)&As[(wm * 64 + mt * 16 + l16) * LDSTRIDE + quad * 8];
#pragma unroll
        for (int nt = 0; nt < 4; ++nt)
            bfr[nt] = *(const bf16x8*)&Bs[(wn * 64 + nt * 16 + l16) * LDSTRIDE + quad * 8];

#pragma unroll
        for (int mt = 0; mt < 4; ++mt)
#pragma unroll
            for (int nt = 0; nt < 4; ++nt)
                acc[mt][nt] = __builtin_amdgcn_mfma_f32_16x16x32_bf16(
                    af[mt], bfr[nt], acc[mt][nt], 0, 0, 0);
    }

#pragma unroll
    for (int nt = 0; nt < 4; ++nt) {
        const int col = col0 + wn * 64 + nt * 16 + l16;
        const float b = bias[col];
#pragma unroll
        for (int mt = 0; mt < 4; ++mt) {
#pragma unroll
            for (int r = 0; r < 4; ++r) {
                const int row = row0 + wm * 64 + mt * 16 + quad * 4 + r;
                if (row < M) {
                    float v = fmaxf(acc[mt][nt][r] + b, 0.f);
                    Cv[(size_t)row * Nc + col] = v;
                }
            }
        }
    }
}

// ------------------- fused MLP: out = relu(A@W1+b1)@W2+b2 + BN stats -------
// M-tile = 128 rows/block, 512 threads (8 waves), 1 block/CU (96KB LDS).
// A 128x256 swz; hid 128x128 swz; 4 chunks of 128 hid cols, fully unrolled.
// pass1: wave owns 16 cols (acc1[8]); pass2: wave owns 32 out cols (acc2[8][2]).
// W2(c) issued before pass1(c); W1(c+1) issued before pass2(c).

__global__ __launch_bounds__(512, 2)
void fused_mlp_kernel(const __bf16* __restrict__ aggb,
                      const __bf16* __restrict__ W1T, const float* __restrict__ b1,
                      const __bf16* __restrict__ W2T, const float* __restrict__ b2,
                      float* __restrict__ out, float* __restrict__ sums, int M)
{
    __shared__ __bf16 As[128 * 256];    // 65536 B, swizzled
    __shared__ __bf16 hidS[128 * 128];  // 32768 B, swizzled

    const int tid  = threadIdx.x;
    const int wid  = tid >> 6;   // 0..7
    const int lane = tid & 63;
    const int quad = lane >> 4;
    const int l16  = lane & 15;
    const int row0 = blockIdx.x * 128;

    // ---- stage A tile (128 x 256 bf16) into LDS, swizzled ----
    {
        const int srow = tid >> 2;        // 0..127
        const int gb8  = (tid & 3) * 8;   // first 8-col group (0,8,16,24)
        const int m = row0 + srow;
        bf16x8 v[8];
        if (m < M) {
            const __bf16* Ap = aggb + (size_t)m * 256 + gb8 * 8;
#pragma unroll
            for (int j = 0; j < 8; ++j) v[j] = *(const bf16x8*)(Ap + j * 8);
        } else {
#pragma unroll
            for (int j = 0; j < 8; ++j)
#pragma unroll
                for (int q = 0; q < 8; ++q) v[j][q] = (__bf16)0.f;
        }
#pragma unroll
        for (int j = 0; j < 8; ++j) {
            const int sg = (gb8 + j) ^ (srow & 7);
            *(bf16x8*)&As[srow * 256 + sg * 8] = v[j];
        }
    }

    f32x4 acc2[8][2];
#pragma unroll
    for (int mt = 0; mt < 8; ++mt)
#pragma unroll
        for (int nt = 0; nt < 2; ++nt) acc2[mt][nt] = (f32x4){0.f, 0.f, 0.f, 0.f};

    // pass1 cols: c*128 + wid*16 + l16 ; pass2 out cols: wid*32 + nt*16 + l16
    const __bf16* W1p = W1T + (size_t)(wid * 16 + l16) * 256 + quad * 8;
    const __bf16* W2p = W2T + (size_t)(wid * 32 + l16) * 512 + quad * 8;

    // prologue: prefetch W1 chunk 0
    bf16x8 w1f[2][8];
#pragma unroll
    for (int kk = 0; kk < 8; ++kk)
        w1f[0][kk] = *(const bf16x8*)(W1p + (size_t)0 + kk * 32);

    __syncthreads();  // A visible

#pragma unroll
    for (int c = 0; c < 4; ++c) {
        const int cur = c & 1;   // static after full unroll
        const int nxt = cur ^ 1;

        // ---- issue W2 loads for this chunk (consumed in pass2 below) ----
        bf16x8 w2f[4][2];
#pragma unroll
        for (int kkl = 0; kkl < 4; ++kkl)
#pragma unroll
            for (int nt = 0; nt < 2; ++nt)
                w2f[kkl][nt] = *(const bf16x8*)(W2p + (size_t)(nt * 16) * 512
                                                + c * 128 + kkl * 32);

        // ---- pass1(c): acc1 = A @ W1[:, c*128 + wid*16 .. +16) ----
        f32x4 acc1[8];
#pragma unroll
        for (int mt = 0; mt < 8; ++mt) acc1[mt] = (f32x4){0.f, 0.f, 0.f, 0.f};
#pragma unroll
        for (int kk = 0; kk < 8; ++kk) {
            const int sg = (kk * 4 + quad) ^ (l16 & 7);
#pragma unroll
            for (int mt = 0; mt < 8; ++mt) {
                bf16x8 af = *(const bf16x8*)&As[(mt * 16 + l16) * 256 + sg * 8];
                acc1[mt] = __builtin_amdgcn_mfma_f32_16x16x32_bf16(
                    af, w1f[cur][kk], acc1[mt], 0, 0, 0);
            }
        }

        __syncthreads();  // pass2(c-1) readers done with hidS

        // ---- write hid(c): col = wid*16 + l16, swizzled ----
        {
            const int lcol = wid * 16 + l16;
            const float bb = b1[c * 128 + lcol];
            const int cg = lcol >> 3;
            const int c7 = lcol & 7;
#pragma unroll
            for (int mt = 0; mt < 8; ++mt)
#pragma unroll
                for (int r = 0; r < 4; ++r) {
                    const int row = mt * 16 + quad * 4 + r;
                    float v = fmaxf(acc1[mt][r] + bb, 0.f);
                    hidS[row * 128 + ((cg ^ (row & 7)) << 3) + c7] = (__bf16)v;
                }
        }
        __syncthreads();  // hid(c) visible

        // ---- prefetch W1 for chunk c+1 (hidden under pass2) ----
        if (c < 3) {
#pragma unroll
            for (int kk = 0; kk < 8; ++kk)
                w1f[nxt][kk] = *(const bf16x8*)(W1p + (size_t)((c + 1) * 128) * 256
                                                + kk * 32);
        }

        // ---- pass2(c): acc2 += hid(c) @ W2[c*128 .. +128, :] ----
#pragma unroll
        for (int kkl = 0; kkl < 4; ++kkl) {
#pragma unroll
            for (int mt = 0; mt < 8; ++mt) {
                const int sg = (kkl * 4 + quad) ^ (l16 & 7);
                bf16x8 hf = *(const bf16x8*)&hidS[(mt * 16 + l16) * 128 + sg * 8];
#pragma unroll
                for (int nt = 0; nt < 2; ++nt)
                    acc2[mt][nt] = __builtin_amdgcn_mfma_f32_16x16x32_bf16(
                        hf, w2f[kkl][nt], acc2[mt][nt], 0, 0, 0);
            }
        }
    }

    // ---- epilogue: bias + store fp32 + BN stats (8-way replicated) ----
    float* srep = sums + (blockIdx.x & 7) * 512;
#pragma unroll
    for (int nt = 0; nt < 2; ++nt) {
        const int col = wid * 32 + nt * 16 + l16;
        const float bb = b2[col];
        float s = 0.f, ss = 0.f;
#pragma unroll
        for (int mt = 0; mt < 8; ++mt) {
#pragma unroll
            for (int r = 0; r < 4; ++r) {
                const int row = row0 + mt * 16 + quad * 4 + r;
                if (row < M) {
                    float v = acc2[mt][nt][r] + bb;
                    out[(size_t)row * 256 + col] = v;
                    s += v; ss += v * v;
                }
            }
        }
        s += __shfl_xor(s, 16); ss += __shfl_xor(ss, 16);
        s += __shfl_xor(s, 32); ss += __shfl_xor(ss, 32);
        if (lane < 16) {
            atomicAdd(&srep[col], s);
            atomicAdd(&srep[256 + col], ss);
        }
    }
}

// WT[l][n][k] = (bf16) W[l][k][n]
__global__ void convert_wt_kernel(const float* __restrict__ W, __bf16* __restrict__ WT,
                                  int K, int Nc, int total)
{
    int i = blockIdx.x * 256 + threadIdx.x;
    if (i >= total) return;
    int kn = K * Nc;
    int l = i / kn;
    int rem = i - l * kn;
    int n = rem / K;
    int k = rem - n * K;
    WT[i] = (__bf16)W[(size_t)l * kn + (size_t)k * Nc + n];
}

// ------------------------ edge sort (once per launch) ----------------------

__global__ void zero_counts_kernel(int* __restrict__ counts, int N)
{
    int i = blockIdx.x * 256 + threadIdx.x;
    if (i < N) counts[i] = 0;
}

__global__ void hist_kernel(const int* __restrict__ ei, int* __restrict__ counts, int E)
{
    int e = blockIdx.x * 256 + threadIdx.x;
    if (e < E) atomicAdd(&counts[ei[E + e]], 1);
}

__global__ void scan1_kernel(const int* __restrict__ counts, int* __restrict__ partial,
                             int* __restrict__ blocksums, int N)
{
    __shared__ int sm[256];
    int i = blockIdx.x * 256 + threadIdx.x;
    int v = (i < N) ? counts[i] : 0;
    sm[threadIdx.x] = v;
    __syncthreads();
    for (int off = 1; off < 256; off <<= 1) {
        int t = 0;
        if ((int)threadIdx.x >= off) t = sm[threadIdx.x - off];
        __syncthreads();
        if ((int)threadIdx.x >= off) sm[threadIdx.x] += t;
        __syncthreads();
    }
    if (i < N) partial[i] = sm[threadIdx.x] - v;
    if (threadIdx.x == 255) blocksums[blockIdx.x] = sm[255];
}

__global__ void scan2_kernel(int* __restrict__ blocksums, int NB)
{
    __shared__ int sm[1024];
    int v = ((int)threadIdx.x < NB) ? blocksums[threadIdx.x] : 0;
    sm[threadIdx.x] = v;
    __syncthreads();
    for (int off = 1; off < 1024; off <<= 1) {
        int t = 0;
        if ((int)threadIdx.x >= off) t = sm[threadIdx.x - off];
        __syncthreads();
        if ((int)threadIdx.x >= off) sm[threadIdx.x] += t;
        __syncthreads();
    }
    if ((int)threadIdx.x < NB) blocksums[threadIdx.x] = sm[threadIdx.x] - v;
}

__global__ void scan3_kernel(const int* __restrict__ partial, const int* __restrict__ blocksums,
                             int* __restrict__ rowptr, int* __restrict__ woff, int N, int E)
{
    int i = blockIdx.x * 256 + threadIdx.x;
    if (i < N) {
        int v = partial[i] + blocksums[blockIdx.x];
        rowptr[i] = v;
        woff[i] = v;
    }
    if (i == 0) rowptr[N] = E;
}

__global__ void scatter_sort_kernel(const int* __restrict__ ei, const int* __restrict__ ea,
                                    int* __restrict__ woff, int* __restrict__ sorted, int E)
{
    int e = blockIdx.x * 256 + threadIdx.x;
    if (e >= E) return;
    int dst = ei[E + e];
    int src = ei[e];
    int c = ea[2 * e] * 3 + ea[2 * e + 1];
    int pos = atomicAdd(&woff[dst], 1);
    sorted[pos] = (src << 4) | c;
}

// ------------------------ per-layer kernels --------------------------------

__global__ void build_table_kernel(const float* __restrict__ E1, const float* __restrict__ E2,
                                   int l, float* __restrict__ tab, float* __restrict__ selfemb,
                                   float* __restrict__ sums)
{
    int b = blockIdx.x;
    int t = threadIdx.x;
    const float* e1 = E1 + (size_t)l * 6 * 256;
    const float* e2 = E2 + (size_t)l * 3 * 256;
    if (b < 9) {
        tab[b * 256 + t] = e1[(b / 3) * 256 + t] + e2[(b % 3) * 256 + t];
    } else {
        selfemb[t] = e1[4 * 256 + t] + e2[0 * 256 + t];
#pragma unroll
        for (int r = 0; r < 16; ++r) sums[r * 256 + t] = 0.f;  // 8 replicas x 512
    }
}

// aggb[n] = bf16( bn(out[n]) + selfemb + sum_e (bn(out[src_e]) + tab[c_e]) )
// Edge loop unrolled x4: 4 sorted[] + 4 row loads in flight.
template<int APPLY_BN>
__global__ __launch_bounds__(256)
void gather_kernel(const float* __restrict__ out, const int* __restrict__ rowptr,
                   const int* __restrict__ sorted, const float* __restrict__ tab,
                   const float* __restrict__ selfemb, const float* __restrict__ scsh,
                   __bf16* __restrict__ aggb, int N)
{
    int n = blockIdx.x * 4 + (threadIdx.x >> 6);
    if (n >= N) return;
    int lane = threadIdx.x & 63;
    int f = lane * 4;

    f32x4 sc, sh;
    if (APPLY_BN) {
        sc = *(const f32x4*)(scsh + f);
        sh = *(const f32x4*)(scsh + 256 + f);
    }

    int r0 = rowptr[n];
    int r1 = rowptr[n + 1];

    f32x4 hv = *(const f32x4*)(out + (size_t)n * 256 + f);
    if (APPLY_BN) hv = hv * sc + sh;
    f32x4 acc = hv + *(const f32x4*)(selfemb + f);

    int e = r0;
#pragma unroll 1
    for (; e + 4 <= r1; e += 4) {
        int v0 = sorted[e + 0];
        int v1 = sorted[e + 1];
        int v2 = sorted[e + 2];
        int v3 = sorted[e + 3];
        f32x4 x0 = *(const f32x4*)(out + (size_t)(v0 >> 4) * 256 + f);
        f32x4 x1 = *(const f32x4*)(out + (size_t)(v1 >> 4) * 256 + f);
        f32x4 x2 = *(const f32x4*)(out + (size_t)(v2 >> 4) * 256 + f);
        f32x4 x3 = *(const f32x4*)(out + (size_t)(v3 >> 4) * 256 + f);
        f32x4 t0 = *(const f32x4*)(tab + (v0 & 15) * 256 + f);
        f32x4 t1 = *(const f32x4*)(tab + (v1 & 15) * 256 + f);
        f32x4 t2 = *(const f32x4*)(tab + (v2 & 15) * 256 + f);
        f32x4 t3 = *(const f32x4*)(tab + (v3 & 15) * 256 + f);
        if (APPLY_BN) {
            x0 = x0 * sc + sh; x1 = x1 * sc + sh;
            x2 = x2 * sc + sh; x3 = x3 * sc + sh;
        }
        acc += (x0 + t0) + (x1 + t1);
        acc += (x2 + t2) + (x3 + t3);
    }
#pragma unroll 1
    for (; e < r1; ++e) {
        int v = sorted[e];
        f32x4 xv = *(const f32x4*)(out + (size_t)(v >> 4) * 256 + f);
        if (APPLY_BN) xv = xv * sc + sh;
        acc += xv + *(const f32x4*)(tab + (v & 15) * 256 + f);
    }
    bf16x4 o;
#pragma unroll
    for (int j = 0; j < 4; ++j) o[j] = (__bf16)acc[j];
    *(bf16x4*)(aggb + (size_t)n * 256 + f) = o;
}

__global__ void bn_finalize_kernel(const float* __restrict__ sums,
                                   const float* __restrict__ gamma,
                                   const float* __restrict__ beta,
                                   int l, int M, float* __restrict__ scsh)
{
    int c = threadIdx.x;  // 256
    float s = 0.f, ss = 0.f;
#pragma unroll
    for (int r = 0; r < 8; ++r) {
        s  += sums[r * 512 + c];
        ss += sums[r * 512 + 256 + c];
    }
    float inv = 1.f / (float)M;
    float mean = s * inv;
    float var = ss * inv - mean * mean;
    float sc = gamma[l * 256 + c] * rsqrtf(var + 1e-5f);
    scsh[c] = sc;
    scsh[256 + c] = beta[l * 256 + c] - mean * sc;
}

// h = out * scale + shift  (final layer only)
__global__ __launch_bounds__(256)
void bn_apply_kernel(const float* __restrict__ out, const float* __restrict__ scsh,
                     float* __restrict__ h, int total4)
{
    int i = blockIdx.x * 256 + threadIdx.x;
    if (i >= total4) return;
    int cg = i & 63;
    f32x4 sc = ((const f32x4*)scsh)[cg];
    f32x4 sh = ((const f32x4*)scsh)[64 + cg];
    f32x4 v = ((const f32x4*)out)[i];
    ((f32x4*)h)[i] = v * sc + sh;
}

extern "C" void kernel_launch(void* const* d_in, const int* in_sizes, int n_in,
                              void* d_out, int out_size, void* d_ws, size_t ws_size,
                              hipStream_t stream)
{
    const float* x     = (const float*)d_in[0];
    const int*   ei    = (const int*)d_in[1];
    const int*   ea    = (const int*)d_in[2];
    const float* Wl    = (const float*)d_in[3];
    const float* bl    = (const float*)d_in[4];
    const float* W1    = (const float*)d_in[5];
    const float* b1    = (const float*)d_in[6];
    const float* W2    = (const float*)d_in[7];
    const float* b2    = (const float*)d_in[8];
    const float* E1    = (const float*)d_in[9];
    const float* E2    = (const float*)d_in[10];
    const float* gamma = (const float*)d_in[11];
    const float* beta  = (const float*)d_in[12];

    const int N = in_sizes[0] / 128;
    const int E = in_sizes[1] / 2;

    // d_out space doubles as the bf16 agg buffer; final bn_apply overwrites it.
    __bf16* aggb = (__bf16*)d_out;               // N x 256 bf16
    float*  hfin = (float*)d_out;                // final output view

    // workspace layout
    float*  out  = (float*)d_ws;                     // N x 256 fp32
    __bf16* WlT  = (__bf16*)(out + (size_t)N * 256); // 256 x 128
    __bf16* W1T  = WlT + 256 * 128;                  // 5 x 512 x 256
    __bf16* W2T  = W1T + 5 * 512 * 256;              // 5 x 256 x 512
    float*  tab  = (float*)(W2T + 5 * 256 * 512);    // 9 x 256
    float*  selfemb = tab + 9 * 256;                 // 256
    float*  sums = selfemb + 256;                    // 8 replicas x 512 = 4096
    float*  scsh = sums + 4096;                      // 512
    int*    counts = (int*)(scsh + 512);             // N
    int*    partial = counts + N;                    // N
    int*    rowptr  = partial + N;                   // N+1
    int*    woff    = rowptr + N + 1;                // N
    int*    sorted  = woff + N;                      // E
    int*    blocksums = sorted + E;                  // <=1024

    const int NB = (N + 255) / 256;
    const int EB = (E + 255) / 256;

    // --- edge sort by dst (edges constant across layers) ---
    zero_counts_kernel<<<NB, 256, 0, stream>>>(counts, N);
    hist_kernel<<<EB, 256, 0, stream>>>(ei, counts, E);
    scan1_kernel<<<NB, 256, 0, stream>>>(counts, partial, blocksums, N);
    scan2_kernel<<<1, 1024, 0, stream>>>(blocksums, NB);
    scan3_kernel<<<NB, 256, 0, stream>>>(partial, blocksums, rowptr, woff, N, E);
    scatter_sort_kernel<<<EB, 256, 0, stream>>>(ei, ea, woff, sorted, E);

    // --- weight conversion (transposed bf16) ---
    convert_wt_kernel<<<(128 * 256 + 255) / 256, 256, 0, stream>>>(Wl, WlT, 128, 256, 128 * 256);
    convert_wt_kernel<<<(5 * 256 * 512 + 255) / 256, 256, 0, stream>>>(W1, W1T, 256, 512, 5 * 256 * 512);
    convert_wt_kernel<<<(5 * 512 * 256 + 255) / 256, 256, 0, stream>>>(W2, W2T, 512, 256, 5 * 512 * 256);

    const int mtiles128 = (N + 127) / 128;
    const int total4 = N * 64;
    const int ew_blocks = (total4 + 255) / 256;
    const int gb = (N + 3) / 4;

    // out = relu(x @ Wl + bl)
    gemm0_kernel<<<dim3(2, mtiles128), 256, 0, stream>>>(x, WlT, bl, out, N, 128, 256);

    for (int l = 0; l < 5; ++l) {
        build_table_kernel<<<10, 256, 0, stream>>>(E1, E2, l, tab, selfemb, sums);
        if (l == 0)
            gather_kernel<0><<<gb, 256, 0, stream>>>(out, rowptr, sorted, tab, selfemb,
                                                     scsh, aggb, N);
        else
            gather_kernel<1><<<gb, 256, 0, stream>>>(out, rowptr, sorted, tab, selfemb,
                                                     scsh, aggb, N);
        fused_mlp_kernel<<<mtiles128, 512, 0, stream>>>(
            aggb, W1T + (size_t)l * 512 * 256, b1 + l * 512,
            W2T + (size_t)l * 256 * 512, b2 + l * 256, out, sums, N);
        bn_finalize_kernel<<<1, 256, 0, stream>>>(sums, gamma, beta, l, N, scsh);
    }
    // final h = bn(out) -> d_out (fp32)
    bn_apply_kernel<<<ew_blocks, 256, 0, stream>>>(out, scsh, hfin, total4);
}